// Round 1
// baseline (1380.115 us; speedup 1.0000x reference)
//
#include <hip/hip_runtime.h>

#define N_NODES 100000
#define N_EDGES 1600000
#define F 128
#define M_PAD 100032       // N_NODES rounded up to 64
#define NCB 1563           // fine buckets = ceil(N_NODES/64)
#define CAP 2048           // padded bucket capacity (mean 1024, max ~1140, 32 sigma safe)
#define EPB 4096           // edges per pass-A block
#define FB_BLOCKS 25000    // feats conv: 6.4M uint pairs / 256
#define W_BLOCKS 64        // W conv: 16384 / 256
#define CC_BLOCKS 7        // ccur init: ceil(NCB/256)

typedef __attribute__((ext_vector_type(8))) short short8;
typedef __attribute__((ext_vector_type(4))) float float4v;

__device__ __forceinline__ unsigned pack_bf16(float x, float y) {
    unsigned ux = __float_as_uint(x), uy = __float_as_uint(y);
    ux = (ux + 0x7fffu + ((ux >> 16) & 1u)) >> 16;       // RNE
    uy = (uy + 0x7fffu + ((uy >> 16) & 1u)) >> 16;
    return ux | (uy << 16);
}

// ---- prep: feats->bf16, W->Wb bf16, ccur init ----
__global__ __launch_bounds__(256) void prep_kernel(
    const float2* __restrict__ feats2, unsigned* __restrict__ featsb,
    const float* __restrict__ W1, const float* __restrict__ W2,
    unsigned* __restrict__ Wbu, int* __restrict__ ccur)
{
    int b = blockIdx.x, t = threadIdx.x;
    if (b < FB_BLOCKS) {
        int i = b * 256 + t;                       // < 6,400,000 exactly
        float2 v = feats2[i];
        featsb[i] = pack_bf16(v.x, v.y);
    } else if (b < FB_BLOCKS + W_BLOCKS) {
        int i = (b - FB_BLOCKS) * 256 + t;         // < 16384 exactly
        int j = i >> 7, c = i & 127;
        const float* s = (c < 64) ? &W1[j * 128 + 2 * c] : &W2[j * 128 + 2 * (c - 64)];
        Wbu[i] = pack_bf16(s[0], s[1]);
    } else {
        int i = (b - FB_BLOCKS - W_BLOCKS) * 256 + t;
        if (i < NCB) ccur[i] = i * CAP;
    }
}

// ---- Pass A: multisplit into 64-node padded buckets; dst-low(6b) in bits 24..31 ----
__global__ __launch_bounds__(256) void passA_kernel(
    const int* __restrict__ esrc, const int* __restrict__ edst,
    const float* __restrict__ evals, int* __restrict__ ccur,
    int2* __restrict__ srtA)
{
    __shared__ int2 sv[EPB];              // 32 KB
    __shared__ unsigned short bkt[EPB];   //  8 KB
    __shared__ int h[NCB], lo[NCB], gbase[NCB];   // 18.8 KB  (total ~59.7 KB)

    const int t = threadIdx.x;
    const int base = blockIdx.x * EPB;
    const int cnt = min(EPB, N_EDGES - base);

    for (int i = t; i < NCB; i += 256) h[i] = 0;
    __syncthreads();

    int rsrc[16], rdst[16], rrank[16];
    float rval[16];
#pragma unroll
    for (int i = 0; i < 16; i++) {
        int e = base + i * 256 + t;
        if (e < N_EDGES) {
            rsrc[i] = esrc[e];
            rdst[i] = edst[e];
            rval[i] = evals[e];
            rrank[i] = atomicAdd(&h[rdst[i] >> 6], 1);
        } else rdst[i] = -1;
    }
    __syncthreads();

    if (t < 64) {   // exclusive scan of h by wave 0
        int carry = 0;
        for (int b0 = 0; b0 < NCB; b0 += 64) {
            int i = b0 + t;
            int x = (i < NCB) ? h[i] : 0;
            int v = x;
#pragma unroll
            for (int d = 1; d < 64; d <<= 1) {
                int y = __shfl_up(v, d);
                if (t >= d) v += y;
            }
            if (i < NCB) lo[i] = v - x + carry;
            carry += __shfl(v, 63);
        }
    }
    __syncthreads();

#pragma unroll
    for (int i = 0; i < 16; i++) {
        if (rdst[i] >= 0) {
            int b = rdst[i] >> 6;
            int s = lo[b] + rrank[i];
            sv[s]  = make_int2(rsrc[i] | ((rdst[i] & 63) << 24),
                               __float_as_int(rval[i]));
            bkt[s] = (unsigned short)b;
        }
    }
    for (int b = t; b < NCB; b += 256) {
        int c = h[b];
        if (c) gbase[b] = atomicAdd(&ccur[b], c);
    }
    __syncthreads();

    for (int s = t; s < cnt; s += 256) {
        int b = bkt[s];
        srtA[gbase[b] + (s - lo[b])] = sv[s];
    }
}

// ---- fused bucket gather: LDS fp32 accumulate over unsorted bucket edges,
//      then epilogue (LE+f, LE*f) -> bf16 Abig. Replaces passB + gather. ----
__global__ __launch_bounds__(256) void bucket_gather_kernel(
    const int* __restrict__ ccur, const int2* __restrict__ srtA,
    const unsigned* __restrict__ fb,   // feats bf16, 64 uints/row
    unsigned* __restrict__ Abig)       // 128 uints/row (sum half, prod half)
{
    __shared__ __align__(16) float acc[64 * 128];   // 32 KB
    const int t = threadIdx.x;
    const int b = blockIdx.x;

    // zero accumulator: 8192 floats by 256 threads, float4 stores
    {
        float4v z = (float4v)(0.f);
#pragma unroll
        for (int j = 0; j < 8; j++)
            *(float4v*)&acc[t * 4 + j * 1024] = z;
    }
    __syncthreads();

    const int base = b * CAP;
    const int cnt = ccur[b] - base;
    const int w = t >> 6, l = t & 63;

    // per-wave contiguous chunk of the bucket's edge list, 8x unrolled
    const int chunk = (cnt + 3) >> 2;
    const int s0 = w * chunk;
    const int e0 = min(s0 + chunk, cnt);
    int i = s0;
    for (; i + 7 < e0; i += 8) {
        int2 m[8];
#pragma unroll
        for (int k = 0; k < 8; k++) m[k] = srtA[base + i + k];
        unsigned p[8];
#pragma unroll
        for (int k = 0; k < 8; k++)
            p[k] = fb[(size_t)(m[k].x & 0x00FFFFFF) * 64 + l];
#pragma unroll
        for (int k = 0; k < 8; k++) {
            float v = __int_as_float(m[k].y);
            int d = (unsigned)m[k].x >> 24;
            float* a = &acc[d * 128 + 2 * l];
            atomicAdd(a,     v * __uint_as_float(p[k] << 16));
            atomicAdd(a + 1, v * __uint_as_float(p[k] & 0xffff0000u));
        }
    }
    for (; i < e0; i++) {
        int2 m = srtA[base + i];
        unsigned p = fb[(size_t)(m.x & 0x00FFFFFF) * 64 + l];
        float v = __int_as_float(m.y);
        int d = (unsigned)m.x >> 24;
        float* a = &acc[d * 128 + 2 * l];
        atomicAdd(a,     v * __uint_as_float(p << 16));
        atomicAdd(a + 1, v * __uint_as_float(p & 0xffff0000u));
    }
    __syncthreads();

    // epilogue: 64 nodes x 64 uint-pairs; per wave one node-row per iter (coalesced)
    const int gn0 = b * 64;
#pragma unroll
    for (int j = 0; j < 16; j++) {
        int idx = t + j * 256;          // 0..4095
        int n = idx >> 6, c = idx & 63;
        int gn = gn0 + n;
        if (gn < N_NODES) {
            unsigned pf = fb[(size_t)gn * 64 + c];
            float f0 = __uint_as_float(pf << 16);
            float f1 = __uint_as_float(pf & 0xffff0000u);
            float2 L = *(const float2*)&acc[n * 128 + 2 * c];
            Abig[(size_t)gn * 128 + c]      = pack_bf16(L.x + f0, L.y + f1);
            Abig[(size_t)gn * 128 + 64 + c] = pack_bf16(L.x * f0, L.y * f1);
        }
    }
}

// ---- GEMM: out = Abig[M x 256] @ Wb[128 x 256]^T + b1 + b2 (no LDS, no barrier)
__global__ __launch_bounds__(256) void gemm_kernel(
    const unsigned short* __restrict__ Abig, const unsigned short* __restrict__ Wb,
    const float* __restrict__ b1, const float* __restrict__ b2,
    float* __restrict__ out)
{
    const int t = threadIdx.x;
    const int w = t >> 6, lane = t & 63;
    const int col = lane & 15;
    const int quad = lane >> 4;
    const int ko = quad * 8;
    const int m0 = blockIdx.x * 64 + w * 16;

    float4v acc[8];
#pragma unroll
    for (int j = 0; j < 8; j++) acc[j] = (float4v)(0.f);

    const unsigned short* arow = Abig + (size_t)(m0 + col) * 256 + ko;
#pragma unroll
    for (int k0 = 0; k0 < 8; k0++) {
        short8 a = *(const short8*)(arow + k0 * 32);
#pragma unroll
        for (int j = 0; j < 8; j++) {
            short8 b = *(const short8*)&Wb[(size_t)(j * 16 + col) * 256 + k0 * 32 + ko];
            acc[j] = __builtin_amdgcn_mfma_f32_16x16x32_bf16(a, b, acc[j], 0, 0, 0);
        }
    }

#pragma unroll
    for (int j = 0; j < 8; j++) {
        int n0 = j * 16 + col;
        float bb = b1[n0] + b2[n0];
#pragma unroll
        for (int r = 0; r < 4; r++) {
            int m = m0 + quad * 4 + r;
            if (m < N_NODES)
                __builtin_nontemporal_store(acc[j][r] + bb, &out[(size_t)m * F + n0]);
        }
    }
}

extern "C" void kernel_launch(void* const* d_in, const int* in_sizes, int n_in,
                              void* d_out, int out_size, void* d_ws, size_t ws_size,
                              hipStream_t stream) {
    const int*   edge_src  = (const int*)d_in[0];
    const int*   edge_dst  = (const int*)d_in[1];
    const float* edge_vals = (const float*)d_in[2];
    const float* feats     = (const float*)d_in[3];
    const float* W1        = (const float*)d_in[4];
    const float* b1        = (const float*)d_in[5];
    const float* W2        = (const float*)d_in[6];
    const float* b2        = (const float*)d_in[7];
    float* out = (float*)d_out;

    // Workspace layout (bytes):
    char* ws = (char*)d_ws;
    unsigned*       featsb = (unsigned*)      (ws);             // 25,600,000
    int2*           srtA   = (int2*)          (ws + 25600000);  // 25,608,192 (1563*2048*8)
    int*            ccur   = (int*)           (ws + 51208192);  //      8,192 (6252 used)
    unsigned*       Wbu    = (unsigned*)      (ws + 51216384);  //     65,536
    unsigned short* Abig   = (unsigned short*)(ws + 51281920);  // 51,216,384 (M_PAD*256*2)
                                                                // end ~102.5 MB

    prep_kernel<<<FB_BLOCKS + W_BLOCKS + CC_BLOCKS, 256, 0, stream>>>(
        (const float2*)feats, featsb, W1, W2, Wbu, ccur);

    passA_kernel<<<(N_EDGES + EPB - 1) / EPB, 256, 0, stream>>>(
        edge_src, edge_dst, edge_vals, ccur, srtA);

    bucket_gather_kernel<<<NCB, 256, 0, stream>>>(
        ccur, srtA, featsb, (unsigned*)Abig);

    gemm_kernel<<<M_PAD / 64, 256, 0, stream>>>(
        Abig, (const unsigned short*)Wbu, b1, b2, out);
}

// Round 3
// 279.413 us; speedup vs baseline: 4.9393x; 4.9393x over previous
//
#include <hip/hip_runtime.h>

#define N_NODES 100000
#define N_EDGES 1600000
#define F 128
#define M_PAD 100032       // N_NODES rounded up to 64
#define NCB 1563           // fine buckets = ceil(N_NODES/64)
#define CAP 2048           // padded bucket capacity (mean 1024, max ~1160, huge margin)
#define EPB 4096           // edges per pass-A block
#define FB_BLOCKS 25000    // feats conv: 6.4M uint pairs / 256
#define W_BLOCKS 64        // W conv: 16384 / 256
#define CC_BLOCKS 7        // ccur init: ceil(NCB/256)

typedef __attribute__((ext_vector_type(8))) short short8;
typedef __attribute__((ext_vector_type(4))) float float4v;

__device__ __forceinline__ unsigned pack_bf16(float x, float y) {
    unsigned ux = __float_as_uint(x), uy = __float_as_uint(y);
    ux = (ux + 0x7fffu + ((ux >> 16) & 1u)) >> 16;       // RNE
    uy = (uy + 0x7fffu + ((uy >> 16) & 1u)) >> 16;
    return ux | (uy << 16);
}

// ---- prep: feats->bf16, W->Wb bf16, ccur init ----
__global__ __launch_bounds__(256) void prep_kernel(
    const float2* __restrict__ feats2, unsigned* __restrict__ featsb,
    const float* __restrict__ W1, const float* __restrict__ W2,
    unsigned* __restrict__ Wbu, int* __restrict__ ccur)
{
    int b = blockIdx.x, t = threadIdx.x;
    if (b < FB_BLOCKS) {
        int i = b * 256 + t;                       // < 6,400,000 exactly
        float2 v = feats2[i];
        featsb[i] = pack_bf16(v.x, v.y);
    } else if (b < FB_BLOCKS + W_BLOCKS) {
        int i = (b - FB_BLOCKS) * 256 + t;         // < 16384 exactly
        int j = i >> 7, c = i & 127;
        const float* s = (c < 64) ? &W1[j * 128 + 2 * c] : &W2[j * 128 + 2 * (c - 64)];
        Wbu[i] = pack_bf16(s[0], s[1]);
    } else {
        int i = (b - FB_BLOCKS - W_BLOCKS) * 256 + t;
        if (i < NCB) ccur[i] = i * CAP;
    }
}

// ---- Pass A: multisplit into 64-node padded buckets; dst-low(6b) in bits 24..31 ----
__global__ __launch_bounds__(256) void passA_kernel(
    const int* __restrict__ esrc, const int* __restrict__ edst,
    const float* __restrict__ evals, int* __restrict__ ccur,
    int2* __restrict__ srtA)
{
    __shared__ int2 sv[EPB];              // 32 KB
    __shared__ unsigned short bkt[EPB];   //  8 KB
    __shared__ int h[NCB], lo[NCB], gbase[NCB];   // 18.8 KB  (total ~59.7 KB)

    const int t = threadIdx.x;
    const int base = blockIdx.x * EPB;
    const int cnt = min(EPB, N_EDGES - base);

    for (int i = t; i < NCB; i += 256) h[i] = 0;
    __syncthreads();

    int rsrc[16], rdst[16], rrank[16];
    float rval[16];
#pragma unroll
    for (int i = 0; i < 16; i++) {
        int e = base + i * 256 + t;
        if (e < N_EDGES) {
            rsrc[i] = esrc[e];
            rdst[i] = edst[e];
            rval[i] = evals[e];
            rrank[i] = atomicAdd(&h[rdst[i] >> 6], 1);
        } else rdst[i] = -1;
    }
    __syncthreads();

    if (t < 64) {   // exclusive scan of h by wave 0
        int carry = 0;
        for (int b0 = 0; b0 < NCB; b0 += 64) {
            int i = b0 + t;
            int x = (i < NCB) ? h[i] : 0;
            int v = x;
#pragma unroll
            for (int d = 1; d < 64; d <<= 1) {
                int y = __shfl_up(v, d);
                if (t >= d) v += y;
            }
            if (i < NCB) lo[i] = v - x + carry;
            carry += __shfl(v, 63);
        }
    }
    __syncthreads();

#pragma unroll
    for (int i = 0; i < 16; i++) {
        if (rdst[i] >= 0) {
            int b = rdst[i] >> 6;
            int s = lo[b] + rrank[i];
            sv[s]  = make_int2(rsrc[i] | ((rdst[i] & 63) << 24),
                               __float_as_int(rval[i]));
            bkt[s] = (unsigned short)b;
        }
    }
    for (int b = t; b < NCB; b += 256) {
        int c = h[b];
        if (c) gbase[b] = atomicAdd(&ccur[b], c);
    }
    __syncthreads();

    for (int s = t; s < cnt; s += 256) {
        int b = bkt[s];
        srtA[gbase[b] + (s - lo[b])] = sv[s];
    }
}

// ---- fused sort+gather per 64-node bucket:
//      LDS fine sort (int atomics only) -> register-accum gather -> bf16 Abig ----
__global__ __launch_bounds__(256) void fused_gather_kernel(
    const int* __restrict__ ccur, const int2* __restrict__ srtA,
    const uint2* __restrict__ fb2,    // feats bf16, 32 uint2/row
    uint2* __restrict__ Abig2)        // 64 uint2/row (sum half, prod half)
{
    __shared__ int2 list[CAP];        // 16 KB
    __shared__ int hist[64], cur[64];

    const int t = threadIdx.x;
    const int b = blockIdx.x;
    const int base = b * CAP;
    const int cnt = ccur[b] - base;

    if (t < 64) hist[t] = 0;
    __syncthreads();

    // phase 1: histogram of dst-low (native int LDS atomics)
    for (int i = t; i < cnt; i += 256)
        atomicAdd(&hist[(unsigned)srtA[base + i].x >> 24], 1);
    __syncthreads();

    // phase 2: exclusive scan of hist[64] by wave 0 -> cur
    if (t < 64) {
        int x = hist[t], v = x;
#pragma unroll
        for (int d = 1; d < 64; d <<= 1) {
            int y = __shfl_up(v, d);
            if (t >= d) v += y;
        }
        cur[t] = v - x;
    }
    __syncthreads();

    // phase 3: scatter into LDS list at atomic positions (L2-hot re-read)
    for (int i = t; i < cnt; i += 256) {
        int2 e = srtA[base + i];
        int d = (unsigned)e.x >> 24;
        int pos = atomicAdd(&cur[d], 1);
        list[pos] = make_int2(e.x & 0x00FFFFFF, e.y);
    }
    __syncthreads();
    // after scatter: cur[n] == end(n), beg(n) == cur[n] - hist[n]

    // phase 4: 4 waves, each owns 16 nodes, 2 in flight (32 lanes each)
    const int w = t >> 6;
    const int lane = t & 63;
    const int h = lane >> 5;          // which of the 2 concurrent nodes
    const int l = lane & 31;          // lane within node

#pragma unroll
    for (int np = 0; np < 16; np += 2) {
        const int nl = w * 16 + np + h;
        const int end = cur[nl];
        int i = end - hist[nl];

        float a0 = 0.f, a1 = 0.f, a2 = 0.f, a3 = 0.f;
        for (; i + 3 < end; i += 4) {
            int2 e0 = list[i], e1 = list[i + 1], e2 = list[i + 2], e3 = list[i + 3];
            uint2 p0 = fb2[(size_t)e0.x * 32 + l];
            uint2 p1 = fb2[(size_t)e1.x * 32 + l];
            uint2 p2 = fb2[(size_t)e2.x * 32 + l];
            uint2 p3 = fb2[(size_t)e3.x * 32 + l];
            float v0 = __int_as_float(e0.y), v1 = __int_as_float(e1.y);
            float v2 = __int_as_float(e2.y), v3 = __int_as_float(e3.y);
            a0 += v0 * __uint_as_float(p0.x << 16) + v1 * __uint_as_float(p1.x << 16)
                + v2 * __uint_as_float(p2.x << 16) + v3 * __uint_as_float(p3.x << 16);
            a1 += v0 * __uint_as_float(p0.x & 0xffff0000u) + v1 * __uint_as_float(p1.x & 0xffff0000u)
                + v2 * __uint_as_float(p2.x & 0xffff0000u) + v3 * __uint_as_float(p3.x & 0xffff0000u);
            a2 += v0 * __uint_as_float(p0.y << 16) + v1 * __uint_as_float(p1.y << 16)
                + v2 * __uint_as_float(p2.y << 16) + v3 * __uint_as_float(p3.y << 16);
            a3 += v0 * __uint_as_float(p0.y & 0xffff0000u) + v1 * __uint_as_float(p1.y & 0xffff0000u)
                + v2 * __uint_as_float(p2.y & 0xffff0000u) + v3 * __uint_as_float(p3.y & 0xffff0000u);
        }
        for (; i < end; i++) {
            int2 e0 = list[i];
            uint2 p0 = fb2[(size_t)e0.x * 32 + l];
            float v0 = __int_as_float(e0.y);
            a0 += v0 * __uint_as_float(p0.x << 16);
            a1 += v0 * __uint_as_float(p0.x & 0xffff0000u);
            a2 += v0 * __uint_as_float(p0.y << 16);
            a3 += v0 * __uint_as_float(p0.y & 0xffff0000u);
        }

        const int gn = b * 64 + nl;
        if (gn < N_NODES) {
            uint2 pf = fb2[(size_t)gn * 32 + l];
            float f0 = __uint_as_float(pf.x << 16);
            float f1 = __uint_as_float(pf.x & 0xffff0000u);
            float f2v = __uint_as_float(pf.y << 16);
            float f3 = __uint_as_float(pf.y & 0xffff0000u);

            uint2 S, P;
            S.x = pack_bf16(a0 + f0, a1 + f1);  S.y = pack_bf16(a2 + f2v, a3 + f3);
            P.x = pack_bf16(a0 * f0, a1 * f1);  P.y = pack_bf16(a2 * f2v, a3 * f3);
            Abig2[(size_t)gn * 64 + l]      = S;
            Abig2[(size_t)gn * 64 + 32 + l] = P;
        }
    }
}

// ---- GEMM: out = Abig[M x 256] @ Wb[128 x 256]^T + b1 + b2 (no LDS, no barrier)
__global__ __launch_bounds__(256) void gemm_kernel(
    const unsigned short* __restrict__ Abig, const unsigned short* __restrict__ Wb,
    const float* __restrict__ b1, const float* __restrict__ b2,
    float* __restrict__ out)
{
    const int t = threadIdx.x;
    const int w = t >> 6, lane = t & 63;
    const int col = lane & 15;
    const int quad = lane >> 4;
    const int ko = quad * 8;
    const int m0 = blockIdx.x * 64 + w * 16;

    float4v acc[8];
#pragma unroll
    for (int j = 0; j < 8; j++) acc[j] = (float4v)(0.f);

    const unsigned short* arow = Abig + (size_t)(m0 + col) * 256 + ko;
#pragma unroll
    for (int k0 = 0; k0 < 8; k0++) {
        short8 a = *(const short8*)(arow + k0 * 32);
#pragma unroll
        for (int j = 0; j < 8; j++) {
            short8 b = *(const short8*)&Wb[(size_t)(j * 16 + col) * 256 + k0 * 32 + ko];
            acc[j] = __builtin_amdgcn_mfma_f32_16x16x32_bf16(a, b, acc[j], 0, 0, 0);
        }
    }

#pragma unroll
    for (int j = 0; j < 8; j++) {
        int n0 = j * 16 + col;
        float bb = b1[n0] + b2[n0];
#pragma unroll
        for (int r = 0; r < 4; r++) {
            int m = m0 + quad * 4 + r;
            if (m < N_NODES)
                __builtin_nontemporal_store(acc[j][r] + bb, &out[(size_t)m * F + n0]);
        }
    }
}

extern "C" void kernel_launch(void* const* d_in, const int* in_sizes, int n_in,
                              void* d_out, int out_size, void* d_ws, size_t ws_size,
                              hipStream_t stream) {
    const int*   edge_src  = (const int*)d_in[0];
    const int*   edge_dst  = (const int*)d_in[1];
    const float* edge_vals = (const float*)d_in[2];
    const float* feats     = (const float*)d_in[3];
    const float* W1        = (const float*)d_in[4];
    const float* b1        = (const float*)d_in[5];
    const float* W2        = (const float*)d_in[6];
    const float* b2        = (const float*)d_in[7];
    float* out = (float*)d_out;

    // Workspace layout (bytes):
    char* ws = (char*)d_ws;
    unsigned*       featsb = (unsigned*)      (ws);             // 25,600,000
    int2*           srtA   = (int2*)          (ws + 25600000);  // 25,608,192 (1563*2048*8)
    int*            ccur   = (int*)           (ws + 51208192);  //      8,192 (6252 used)
    unsigned*       Wbu    = (unsigned*)      (ws + 51216384);  //     65,536
    unsigned short* Abig   = (unsigned short*)(ws + 51281920);  // 51,216,384 (M_PAD*256*2)
                                                                // end ~102.5 MB

    prep_kernel<<<FB_BLOCKS + W_BLOCKS + CC_BLOCKS, 256, 0, stream>>>(
        (const float2*)feats, featsb, W1, W2, Wbu, ccur);

    passA_kernel<<<(N_EDGES + EPB - 1) / EPB, 256, 0, stream>>>(
        edge_src, edge_dst, edge_vals, ccur, srtA);

    fused_gather_kernel<<<NCB, 256, 0, stream>>>(
        ccur, srtA, (const uint2*)featsb, (uint2*)Abig);

    gemm_kernel<<<M_PAD / 64, 256, 0, stream>>>(
        Abig, (const unsigned short*)Wbu, b1, b2, out);
}